// Round 8
// baseline (59.992 us; speedup 1.0000x reference)
//
#include <hip/hip_runtime.h>
#include <hip/hip_bf16.h>

#define M 256
#define NOUT 1024
#define KTOT 16384
#define RANK 16
#define NKC 32          // split-K blocks
#define KCHUNK 512      // K per gemm block (2 LDS phases of 256)

typedef __attribute__((ext_vector_type(8)))  short bf16x8_t;
typedef __attribute__((ext_vector_type(4)))  float f32x4_t;
typedef __attribute__((ext_vector_type(16))) float f32x16_t;
typedef __attribute__((ext_vector_type(8)))  unsigned short u16x8_t;
typedef __attribute__((ext_vector_type(4)))  unsigned short u16x4_t;

static __device__ __forceinline__ unsigned short f2bf(float f) {
  unsigned u = __builtin_bit_cast(unsigned, f);
  u += 0x7FFFu + ((u >> 16) & 1u);   // round-to-nearest-even
  return (unsigned short)(u >> 16);
}
static __device__ __forceinline__ float bf2f(unsigned short h) {
  unsigned u = ((unsigned)h) << 16;
  return __builtin_bit_cast(float, u);
}

// X natural row-major bf16: X[b][k] = input[b][k>>4] * coef[b][k&15].
// Thread (b,i) writes 32 B contiguous; wave writes 2 KB contiguous.
__global__ __launch_bounds__(256) void build_x_kernel(
    const float* __restrict__ input, const float* __restrict__ coef,
    unsigned short* __restrict__ X)
{
  int idx = blockIdx.x * 256 + threadIdx.x;   // idx = b*1024 + i
  int b = idx >> 10;
  float in = input[idx];
  const float* c = coef + b * RANK;
  u16x8_t lo, hi;                              // k = i*16 + r
  #pragma unroll
  for (int r = 0; r < 8; ++r) lo[r] = f2bf(in * c[r]);
  #pragma unroll
  for (int r = 0; r < 8; ++r) hi[r] = f2bf(in * c[8 + r]);
  u16x8_t* dst = (u16x8_t*)(X + (size_t)idx * 16);
  dst[0] = lo;
  dst[1] = hi;
}

// out^T GEMM: part[kc][o][b] (bf16) = sum_{k in chunk kc} W[o,k] * X[b,k]
// via mfma_f32_32x32x16_bf16. Block: 32 o-rows x 256 b x K=512; 4 waves share
// the A-frag (W) from a 16 KB LDS tile; wave w owns b-tiles {2w, 2w+1}.
// Grid 1024 = 32 ot x 32 kc -> 4 blocks/CU, 16 waves/CU.
//
// KEY (DRAM page efficiency): W is staged so each wave-instruction reads ONE
// ROW's 1 KB phase-chunk CONTIGUOUSLY (8 instrs/phase = 32 rows x 1 KB), cvt
// fp32->bf16 in-register, ds_write into an XOR-swizzled tile; fragment
// ds_read_b128 is conflict-free. W hits DRAM in 1 KB page bursts, once
// grid-wide. X (B-frag, bf16 natural layout) is read per-step directly from
// global (L1-cached across steps; XCD-pinned kc keeps its slice in one L2).
__global__ __launch_bounds__(256, 4) void gemm_kernel(
    const unsigned short* __restrict__ X, const float* __restrict__ W,
    unsigned short* __restrict__ part)
{
  __shared__ unsigned short Ws[32 * 32 * 8];   // [row][slot16^row][8 bf16] = 16 KB

  const int tid = threadIdx.x;
  const int w = tid >> 6, l = tid & 63;
  const int l31 = l & 31, l5 = l >> 5;

  // XCD pinning: xcd = lin&7 fixed per kc group -> X slice lives in one L2.
  const int lin = blockIdx.x;
  const int xcd = lin & 7, ot = (lin >> 3) & 31, gg = lin >> 8;
  const int kc = xcd * 4 + gg;

  // stage source: thread covers 16 B of row (ot*32 + i*4 + w) at float col
  // (l*4) within the 256-float phase chunk; wave-instr = one row x 1 KB.
  const float* wg = W + (size_t)(ot * 32 + w) * KTOT + kc * KCHUNK + l * 4;

  // X fragment pointers: B-frag lane: b-row = jtile*32 + l31, 8 k at l5*8.
  const unsigned short* xp0 = X + (size_t)(w * 64 + l31) * KTOT + kc * KCHUNK + l5 * 8;
  const unsigned short* xp1 = xp0 + (size_t)32 * KTOT;

  f32x16_t acc0 = (f32x16_t)(0.0f), acc1 = (f32x16_t)(0.0f);
  float4 g0, g1, g2, g3, g4, g5, g6, g7;
  bf16x8_t x0a, x0b, x1a, x1b;

  #define ISSUEG(P)                                                          \
    { g0 = *(const float4*)(wg + (P) * 256);                                 \
      g1 = *(const float4*)(wg + (P) * 256 + 1 * 4 * KTOT);                  \
      g2 = *(const float4*)(wg + (P) * 256 + 2 * 4 * KTOT);                  \
      g3 = *(const float4*)(wg + (P) * 256 + 3 * 4 * KTOT);                  \
      g4 = *(const float4*)(wg + (P) * 256 + 4 * 4 * KTOT);                  \
      g5 = *(const float4*)(wg + (P) * 256 + 5 * 4 * KTOT);                  \
      g6 = *(const float4*)(wg + (P) * 256 + 6 * 4 * KTOT);                  \
      g7 = *(const float4*)(wg + (P) * 256 + 7 * 4 * KTOT); }

  // thread's slot: row r = i*4 + w, 16B-slot s16 = l>>1 (^ r), half = l&1.
  #define WR1(GI, I)                                                         \
    { int r = (I) * 4 + w;                                                   \
      u16x4_t v;                                                             \
      v[0] = f2bf(GI.x); v[1] = f2bf(GI.y);                                  \
      v[2] = f2bf(GI.z); v[3] = f2bf(GI.w);                                  \
      *(u16x4_t*)&Ws[((r * 32) + ((l >> 1) ^ r)) * 8 + (l & 1) * 4] = v; }
  #define WRITEG                                                             \
    WR1(g0, 0) WR1(g1, 1) WR1(g2, 2) WR1(g3, 3)                              \
    WR1(g4, 4) WR1(g5, 5) WR1(g6, 6) WR1(g7, 7)

  // A-frag: lane row = l31, k-slot s16 = (t&15)*2 + l5, swizzled by ^row.
  #define STEPL(T, P)                                                        \
    { bf16x8_t af = *(const bf16x8_t*)                                       \
          &Ws[((l31 * 32) + ((((T) & 15) * 2 + l5) ^ l31)) * 8];             \
      acc0 = __builtin_amdgcn_mfma_f32_32x32x16_bf16(af, x##P##a, acc0, 0, 0, 0); \
      acc1 = __builtin_amdgcn_mfma_f32_32x32x16_bf16(af, x##P##b, acc1, 0, 0, 0); \
      x##P##a = *(const bf16x8_t*)(xp0 + ((T) + 2) * 16);                    \
      x##P##b = *(const bf16x8_t*)(xp1 + ((T) + 2) * 16); }
  #define STEPN(T, P)                                                        \
    { bf16x8_t af = *(const bf16x8_t*)                                       \
          &Ws[((l31 * 32) + ((((T) & 15) * 2 + l5) ^ l31)) * 8];             \
      acc0 = __builtin_amdgcn_mfma_f32_32x32x16_bf16(af, x##P##a, acc0, 0, 0, 0); \
      acc1 = __builtin_amdgcn_mfma_f32_32x32x16_bf16(af, x##P##b, acc1, 0, 0, 0); }

  // ---- prologue: phase-0 stage + X prefetch ----
  ISSUEG(0)
  x0a = *(const bf16x8_t*)(xp0);       x0b = *(const bf16x8_t*)(xp1);
  x1a = *(const bf16x8_t*)(xp0 + 16);  x1b = *(const bf16x8_t*)(xp1 + 16);
  WRITEG                                // compiler auto-waits the g loads
  __syncthreads();
  ISSUEG(1)                             // phase-1 stage in flight over phase 0

  // ---- phase 0: steps 0..15 ----
  STEPL(0,0)  STEPL(1,1)  STEPL(2,0)  STEPL(3,1)
  STEPL(4,0)  STEPL(5,1)  STEPL(6,0)  STEPL(7,1)
  STEPL(8,0)  STEPL(9,1)  STEPL(10,0) STEPL(11,1)
  STEPL(12,0) STEPL(13,1) STEPL(14,0) STEPL(15,1)

  __syncthreads();                      // all reads of phase-0 tile done
  WRITEG                                // auto-waits phase-1 g loads
  __syncthreads();

  // ---- phase 1: steps 16..31 ----
  STEPL(16,0) STEPL(17,1) STEPL(18,0) STEPL(19,1)
  STEPL(20,0) STEPL(21,1) STEPL(22,0) STEPL(23,1)
  STEPL(24,0) STEPL(25,1) STEPL(26,0) STEPL(27,1)
  STEPL(28,0) STEPL(29,1) STEPN(30,0) STEPN(31,1)

  // ---- epilogue: D layout col(b)=l&31, row(o)=(q&3)+8*(q>>2)+4*l5 ----
  unsigned short* p = part + (size_t)kc * (NOUT * 256);
  #pragma unroll
  for (int q = 0; q < 16; ++q) {
    int o = ot * 32 + (q & 3) + 8 * (q >> 2) + 4 * l5;
    p[(size_t)o * 256 + w * 64 + l31]      = f2bf(acc0[q]);
    p[(size_t)o * 256 + w * 64 + 32 + l31] = f2bf(acc1[q]);
  }
  #undef ISSUEG
  #undef WR1
  #undef WRITEG
  #undef STEPL
  #undef STEPN
}

// out[b][o] = sum_kc bf2f(part[kc][o][b]) + sum_r bias[o][r]*coef[b][r]
// Block: 8 o-rows x 256 b. Coalesced part reads; LDS transpose; coalesced
// out writes.
__global__ __launch_bounds__(256) void reduce_bias_kernel(
    const unsigned short* __restrict__ part, const float* __restrict__ bias,
    const float* __restrict__ coef, float* __restrict__ out)
{
  __shared__ float lds[8 * 256];
  const int t = threadIdx.x;
  const int o = blockIdx.x * 8 + (t >> 5);
  const int b8 = (t & 31) * 8;

  float s[8];
  #pragma unroll
  for (int j = 0; j < 8; ++j) s[j] = 0.f;

  #pragma unroll 8
  for (int kc = 0; kc < NKC; ++kc) {
    u16x8_t v = *(const u16x8_t*)(part + ((size_t)kc * NOUT + o) * 256 + b8);
    #pragma unroll
    for (int j = 0; j < 8; ++j) s[j] += bf2f(v[j]);
  }

  const f32x4_t* br = (const f32x4_t*)(bias + (size_t)o * RANK);
  f32x4_t b0 = br[0], b1 = br[1], b2 = br[2], b3 = br[3];
  #pragma unroll
  for (int j = 0; j < 8; ++j) {
    const f32x4_t* cr = (const f32x4_t*)(coef + (size_t)(b8 + j) * RANK);
    f32x4_t c0 = cr[0], c1 = cr[1], c2 = cr[2], c3 = cr[3];
    float bb = 0.f;
    #pragma unroll
    for (int e = 0; e < 4; ++e)
      bb += b0[e] * c0[e] + b1[e] * c1[e] + b2[e] * c2[e] + b3[e] * c3[e];
    s[j] += bb;
  }

  // transpose 8x256 tile through LDS
  f32x4_t v0, v1;
  v0[0] = s[0]; v0[1] = s[1]; v0[2] = s[2]; v0[3] = s[3];
  v1[0] = s[4]; v1[1] = s[5]; v1[2] = s[6]; v1[3] = s[7];
  *(f32x4_t*)&lds[(t >> 5) * 256 + b8]     = v0;
  *(f32x4_t*)&lds[(t >> 5) * 256 + b8 + 4] = v1;
  __syncthreads();

  const int b = t;
  float g[8];
  #pragma unroll
  for (int j = 0; j < 8; ++j) g[j] = lds[j * 256 + b];
  float4* dst = (float4*)(out + (size_t)b * NOUT + blockIdx.x * 8);
  dst[0] = make_float4(g[0], g[1], g[2], g[3]);
  dst[1] = make_float4(g[4], g[5], g[6], g[7]);
}

extern "C" void kernel_launch(void* const* d_in, const int* in_sizes, int n_in,
                              void* d_out, int out_size, void* d_ws, size_t ws_size,
                              hipStream_t stream) {
  const float* input = (const float*)d_in[0];   // (256, 1024)
  const float* coef  = (const float*)d_in[1];   // (256, 16)
  const float* W     = (const float*)d_in[2];   // (1024, 1024, 16) -> (1024, 16384)
  const float* bias  = (const float*)d_in[3];   // (1024, 16)
  float* out = (float*)d_out;                   // (256, 1024)

  unsigned short* X    = (unsigned short*)d_ws;                               // 8 MiB bf16
  unsigned short* part = (unsigned short*)((char*)d_ws + (size_t)M * KTOT * 2); // 16 MiB bf16

  build_x_kernel<<<(M * 1024) / 256, 256, 0, stream>>>(input, coef, X);
  gemm_kernel<<<1024, 256, 0, stream>>>(X, W, part);
  reduce_bias_kernel<<<NOUT / 8, 256, 0, stream>>>(part, bias, coef, out);
}

// Round 9
// 37.190 us; speedup vs baseline: 1.6132x; 1.6132x over previous
//
#include <hip/hip_runtime.h>
#include <hip/hip_bf16.h>

#define M 256
#define NOUT 1024
#define KTOT 16384
#define RANK 16
#define NKC 32          // split-K factor
#define KCHUNK 512      // K per block
#define BK 32           // K per phase
#define NPH 16          // phases per block
#define BO 64           // o-rows per block

typedef __attribute__((ext_vector_type(8)))  short bf16x8_t;
typedef __attribute__((ext_vector_type(4)))  float f32x4_t;
typedef __attribute__((ext_vector_type(16))) float f32x16_t;
typedef __attribute__((ext_vector_type(8)))  unsigned short u16x8_t;

static __device__ __forceinline__ unsigned short f2bf(float f) {
  unsigned u = __builtin_bit_cast(unsigned, f);
  u += 0x7FFFu + ((u >> 16) & 1u);   // round-to-nearest-even
  return (unsigned short)(u >> 16);
}
static __device__ __forceinline__ float bf2f(unsigned short h) {
  unsigned u = ((unsigned)h) << 16;
  return __builtin_bit_cast(float, u);
}
static __device__ __forceinline__ bf16x8_t cvt8(f32x4_t a, f32x4_t b) {
  bf16x8_t r;
  r[0] = (short)f2bf(a[0]); r[1] = (short)f2bf(a[1]);
  r[2] = (short)f2bf(a[2]); r[3] = (short)f2bf(a[3]);
  r[4] = (short)f2bf(b[0]); r[5] = (short)f2bf(b[1]);
  r[6] = (short)f2bf(b[2]); r[7] = (short)f2bf(b[3]);
  return r;
}

// X stored in 32-k chunks, slot-swizzled at build time (rule #21):
//   element (b,k): chunk = k>>5, slot = (k&31)>>3 (0..3), el = k&7
//   pos = ((chunk*256 + b)*4 + (slot ^ (b&3)))*8 + el            (bf16)
// GEMM stages a chunk with a PURE LINEAR copy (1 KB contiguous per wave
// instr); fragment ds_read_b128 at slot (ks*2+l5)^(l31&3) is ~4-way max.
__global__ __launch_bounds__(256) void build_x_kernel(
    const float* __restrict__ input, const float* __restrict__ coef,
    unsigned short* __restrict__ X)
{
  int idx = blockIdx.x * 256 + threadIdx.x;   // idx = b*1024 + i
  int b = idx >> 10, i = idx & 1023;
  float in = input[idx];
  const float* c = coef + b * RANK;
  u16x8_t lo, hi;                              // k = i*16 + r
  #pragma unroll
  for (int r = 0; r < 8; ++r) lo[r] = f2bf(in * c[r]);
  #pragma unroll
  for (int r = 0; r < 8; ++r) hi[r] = f2bf(in * c[8 + r]);
  int chunk = i >> 1;            // (i*16) >> 5
  int s0 = (i & 1) * 2;          // slots s0 (r<8), s0+1 (r>=8)
  int sw = b & 3;
  size_t base = ((size_t)chunk * 256 + b) * 32;    // shorts
  *(u16x8_t*)(X + base + (size_t)((s0    ) ^ sw) * 8) = lo;
  *(u16x8_t*)(X + base + (size_t)((s0 | 1) ^ sw) * 8) = hi;
}

// out^T GEMM: part[kc][o][b] (bf16) = sum_{k in chunk kc} W[o,k] * X[b,k]
// via mfma_f32_32x32x16_bf16, A = W-frag (row=l&31 -> o), B = X-frag
// (col=l&31 -> b). Block: 64 o x 256 b x K=512; 512 threads (8 waves,
// wave = 32 o x 64 b); 48 KB LDS -> 2 blocks/CU = 16 waves/CU.
// BOTH operands staged through LDS via global_load_lds (all global reads
// segment-contiguous: X 1 KB linear/wave-instr; W 8x128B permuted rows).
// W read EXACTLY ONCE grid-wide (no o/b-split redundancy). 16 phases of
// BK=32, double-buffered, stage(p+1)-issue-first then compute(p) then one
// __syncthreads -> stage has a full phase to land; the two blocks per CU
// interleave their barrier drains, keeping the HBM stream continuous.
__global__ __launch_bounds__(512, 2) void gemm_kernel(
    const unsigned short* __restrict__ X, const float* __restrict__ W,
    unsigned short* __restrict__ part)
{
  __shared__ unsigned short Xs0[256 * 4 * 8];   // 16 KB [b][slot'][8]
  __shared__ unsigned short Xs1[256 * 4 * 8];   // 16 KB
  __shared__ float          Wf0[64 * 8 * 4];    //  8 KB [o'][slot'][4]
  __shared__ float          Wf1[64 * 8 * 4];    //  8 KB

  const int tid = threadIdx.x;                  // 0..511
  const int w = tid >> 6, lane = tid & 63;
  const int l31 = lane & 31, l5 = lane >> 5;
  const int ow = w & 1, btp = w >> 1;           // wave: o-tile ow, b-tiles {2btp,2btp+1}

  // XCD pinning: per XCD 4 kc x 16 ot -> the 16 blocks sharing a kc X-slice
  // (256 KB) run concurrently on one XCD's L2 (4 slices = 1 MB).
  const int lin = blockIdx.x;
  const int idx = lin >> 3;
  const int kc = (lin & 7) * 4 + (idx & 3);
  const int ot = idx >> 2;                      // 0..15

  const int o0 = ot * BO;
  const int kb0 = kc * KCHUNK;

  f32x16_t acc0 = (f32x16_t)(0.0f), acc1 = (f32x16_t)(0.0f);

  // W stage coords: thread t covers 16 B piece (o' = t>>3, slot s = t&7) of
  // the 128 B phase row-chunk; SOURCE slot is s ^ (o'&7) (inverse swizzle),
  // LDS dest linear -> LDS slot s holds source slot s^(o'&7).
  const int wo_ = tid >> 3, ws_ = tid & 7;
  const float* wsrc = W + (size_t)(o0 + wo_) * KTOT + kb0 + ((ws_ ^ (wo_ & 7)) * 4);
  const unsigned short* xbase = X + (size_t)(kc * NPH) * (256 * 32);

  #define SB __builtin_amdgcn_sched_barrier(0);

  #define STAGE(P, XB, WB)                                                   \
    {                                                                        \
      __builtin_amdgcn_global_load_lds(                                      \
          (const __attribute__((address_space(1))) unsigned int*)            \
              (wsrc + (P) * 32),                                             \
          (__attribute__((address_space(3))) unsigned int*)(&WB[tid * 4]),   \
          16, 0, 0);                                                         \
      _Pragma("unroll")                                                      \
      for (int j = 0; j < 2; ++j) {                                          \
        int q = j * 512 + tid;                                               \
        __builtin_amdgcn_global_load_lds(                                    \
            (const __attribute__((address_space(1))) unsigned int*)          \
                (xbase + (size_t)(P) * 8192 + q * 8),                        \
            (__attribute__((address_space(3))) unsigned int*)(&XB[q * 8]),   \
            16, 0, 0);                                                       \
      }                                                                      \
    }

  #define COMPUTE(XB, WB)                                                   \
    {                                                                       \
      _Pragma("unroll")                                                     \
      for (int ks = 0; ks < 2; ++ks) {                                      \
        int o = ow * 32 + l31;                                              \
        f32x4_t a0 = *(const f32x4_t*)                                      \
            &WB[(o * 8 + ((ks * 4 + l5 * 2)     ^ (l31 & 7))) * 4];         \
        f32x4_t a1 = *(const f32x4_t*)                                      \
            &WB[(o * 8 + ((ks * 4 + l5 * 2 + 1) ^ (l31 & 7))) * 4];         \
        bf16x8_t af = cvt8(a0, a1);                                         \
        int b0r = (btp * 2) * 32 + l31;                                     \
        int b1r = (btp * 2 + 1) * 32 + l31;                                 \
        bf16x8_t xf0 = *(const bf16x8_t*)                                   \
            &XB[(b0r * 4 + ((ks * 2 + l5) ^ (l31 & 3))) * 8];               \
        bf16x8_t xf1 = *(const bf16x8_t*)                                   \
            &XB[(b1r * 4 + ((ks * 2 + l5) ^ (l31 & 3))) * 8];               \
        acc0 = __builtin_amdgcn_mfma_f32_32x32x16_bf16(af, xf0, acc0, 0, 0, 0); \
        acc1 = __builtin_amdgcn_mfma_f32_32x32x16_bf16(af, xf1, acc1, 0, 0, 0); \
      }                                                                     \
    }

  #define BAR __syncthreads();

  // ---- prologue ----
  STAGE(0, Xs0, Wf0) BAR

  // ---- 16 phases, double-buffered, stage-first ----
  STAGE(1,  Xs1, Wf1) SB COMPUTE(Xs0, Wf0) BAR
  STAGE(2,  Xs0, Wf0) SB COMPUTE(Xs1, Wf1) BAR
  STAGE(3,  Xs1, Wf1) SB COMPUTE(Xs0, Wf0) BAR
  STAGE(4,  Xs0, Wf0) SB COMPUTE(Xs1, Wf1) BAR
  STAGE(5,  Xs1, Wf1) SB COMPUTE(Xs0, Wf0) BAR
  STAGE(6,  Xs0, Wf0) SB COMPUTE(Xs1, Wf1) BAR
  STAGE(7,  Xs1, Wf1) SB COMPUTE(Xs0, Wf0) BAR
  STAGE(8,  Xs0, Wf0) SB COMPUTE(Xs1, Wf1) BAR
  STAGE(9,  Xs1, Wf1) SB COMPUTE(Xs0, Wf0) BAR
  STAGE(10, Xs0, Wf0) SB COMPUTE(Xs1, Wf1) BAR
  STAGE(11, Xs1, Wf1) SB COMPUTE(Xs0, Wf0) BAR
  STAGE(12, Xs0, Wf0) SB COMPUTE(Xs1, Wf1) BAR
  STAGE(13, Xs1, Wf1) SB COMPUTE(Xs0, Wf0) BAR
  STAGE(14, Xs0, Wf0) SB COMPUTE(Xs1, Wf1) BAR
  STAGE(15, Xs1, Wf1) SB COMPUTE(Xs0, Wf0) BAR
  COMPUTE(Xs1, Wf1)

  // ---- epilogue: D layout col(b)=l&31, row(o)=(q&3)+8*(q>>2)+4*l5 ----
  unsigned short* p = part + (size_t)kc * (NOUT * 256);
  #pragma unroll
  for (int q = 0; q < 16; ++q) {
    int o = o0 + ow * 32 + (q & 3) + 8 * (q >> 2) + 4 * l5;
    p[(size_t)o * 256 + (btp * 2) * 32 + l31]     = f2bf(acc0[q]);
    p[(size_t)o * 256 + (btp * 2 + 1) * 32 + l31] = f2bf(acc1[q]);
  }
  #undef STAGE
  #undef COMPUTE
  #undef BAR
  #undef SB
}

// out[b][o] = sum_kc bf2f(part[kc][o][b]) + sum_r bias[o][r]*coef[b][r]
// Block: 8 o-rows x 256 b; coalesced part reads; LDS transpose; coalesced
// out writes.
__global__ __launch_bounds__(256) void reduce_bias_kernel(
    const unsigned short* __restrict__ part, const float* __restrict__ bias,
    const float* __restrict__ coef, float* __restrict__ out)
{
  __shared__ float lds[8 * 256];
  const int t = threadIdx.x;
  const int o = blockIdx.x * 8 + (t >> 5);
  const int b8 = (t & 31) * 8;

  float s[8];
  #pragma unroll
  for (int j = 0; j < 8; ++j) s[j] = 0.f;

  #pragma unroll 8
  for (int kc = 0; kc < NKC; ++kc) {
    u16x8_t v = *(const u16x8_t*)(part + ((size_t)kc * NOUT + o) * 256 + b8);
    #pragma unroll
    for (int j = 0; j < 8; ++j) s[j] += bf2f(v[j]);
  }

  const f32x4_t* br = (const f32x4_t*)(bias + (size_t)o * RANK);
  f32x4_t b0 = br[0], b1 = br[1], b2 = br[2], b3 = br[3];
  #pragma unroll
  for (int j = 0; j < 8; ++j) {
    const f32x4_t* cr = (const f32x4_t*)(coef + (size_t)(b8 + j) * RANK);
    f32x4_t c0 = cr[0], c1 = cr[1], c2 = cr[2], c3 = cr[3];
    float bb = 0.f;
    #pragma unroll
    for (int e = 0; e < 4; ++e)
      bb += b0[e] * c0[e] + b1[e] * c1[e] + b2[e] * c2[e] + b3[e] * c3[e];
    s[j] += bb;
  }

  f32x4_t v0, v1;
  v0[0] = s[0]; v0[1] = s[1]; v0[2] = s[2]; v0[3] = s[3];
  v1[0] = s[4]; v1[1] = s[5]; v1[2] = s[6]; v1[3] = s[7];
  *(f32x4_t*)&lds[(t >> 5) * 256 + b8]     = v0;
  *(f32x4_t*)&lds[(t >> 5) * 256 + b8 + 4] = v1;
  __syncthreads();

  const int b = t;
  float g[8];
  #pragma unroll
  for (int j = 0; j < 8; ++j) g[j] = lds[j * 256 + b];
  float4* dst = (float4*)(out + (size_t)b * NOUT + blockIdx.x * 8);
  dst[0] = make_float4(g[0], g[1], g[2], g[3]);
  dst[1] = make_float4(g[4], g[5], g[6], g[7]);
}

extern "C" void kernel_launch(void* const* d_in, const int* in_sizes, int n_in,
                              void* d_out, int out_size, void* d_ws, size_t ws_size,
                              hipStream_t stream) {
  const float* input = (const float*)d_in[0];   // (256, 1024)
  const float* coef  = (const float*)d_in[1];   // (256, 16)
  const float* W     = (const float*)d_in[2];   // (1024, 1024, 16) -> (1024, 16384)
  const float* bias  = (const float*)d_in[3];   // (1024, 16)
  float* out = (float*)d_out;                   // (256, 1024)

  unsigned short* X    = (unsigned short*)d_ws;                               // 8 MiB bf16
  unsigned short* part = (unsigned short*)((char*)d_ws + (size_t)M * KTOT * 2); // 16 MiB bf16

  build_x_kernel<<<(M * 1024) / 256, 256, 0, stream>>>(input, coef, X);
  gemm_kernel<<<512, 512, 0, stream>>>(X, W, part);
  reduce_bias_kernel<<<NOUT / 8, 256, 0, stream>>>(part, bias, coef, out);
}